// Round 4
// baseline (169.980 us; speedup 1.0000x reference)
//
#include <hip/hip_runtime.h>
#include <stdint.h>

// out = conv3x3_zeropad(s, W_eff), s = 3x3 reflect-pad box sum of x (B=16,C=64,H=W=128)
// R9: fused kernel (R7/R8 structure, verified passing) with staging rebuilt for
// memory-level parallelism: all 51 float4 loads hoisted into register arrays
// (one latency exposure) before the sum/patch/LDS-write pass. R3 showed 88
// VGPRs -> serialized loads -> latency-bound (80us, all pipes <10%).
// MFMA loop / swizzle / epilogue / weff byte-identical to verified R4 conv.

#define THETA 0.7f

typedef __attribute__((ext_vector_type(8))) short bf16x8;
typedef __attribute__((ext_vector_type(16))) float f32x16;

__device__ inline unsigned short f2bf(float f) {
    unsigned u = __float_as_uint(f);
    u = (u + 0x7FFFu + ((u >> 16) & 1u)) >> 16;   // RNE
    return (unsigned short)u;
}

// ---------------------------------------------------------------------------
// Kernel 1: W_eff -> Wt2 bf16, lane-contiguous MFMA-A layout (verified):
// Wt2[(((tap*4+ic)*2+mf)*64 + lane)*8 + j] = W_eff[o][ch][tap]
//   o = mf*32 + (lane&31), ch = ic*16 + (lane>>5)*8 + j
// ---------------------------------------------------------------------------
__global__ void weff_kernel(const float* __restrict__ W, unsigned short* __restrict__ Wt2) {
    int t = blockIdx.x * blockDim.x + threadIdx.x;   // 512 threads
    if (t >= 512) return;
    int o = t >> 3;
    int ch8 = t & 7;
    int c0 = ch8 * 8;
    int ic = ch8 >> 1;
    int mf = o >> 5;
    int lane = (o & 31) | ((ch8 & 1) << 5);

    float v[8][9];
    float tsum[8];
#pragma unroll
    for (int j = 0; j < 8; j++) {
        const float* w = W + ((size_t)o * 64 + c0 + j) * 9;
        float sum = 0.f;
#pragma unroll
        for (int k = 0; k < 9; k++) { v[j][k] = w[k]; sum += v[j][k]; }
        tsum[j] = sum;
    }
#pragma unroll
    for (int tap = 0; tap < 9; tap++) {
        unsigned short* dst = Wt2 + (((size_t)(tap * 4 + ic) * 2 + mf) * 64 + lane) * 8;
#pragma unroll
        for (int j = 0; j < 8; j++) {
            float val = v[j][tap] - ((tap == 4) ? THETA * tsum[j] : 0.f);
            dst[j] = f2bf(val);
        }
    }
}

// ---------------------------------------------------------------------------
// Staging: one s-row (66 slots x 64 ch) of the conv LDS tile, computed from x.
// Thread owns channel c. LOAD PHASE: 3 x-rows x 17 float4 hoisted into named
// register arrays (all 51 loads in flight -> single HBM latency exposure).
// SUM PHASE: vertical 3-sum into statically-indexed v[68] (v[j] <-> mapped w),
// register reflect-patches, horizontal 3-sum, zero-pad of OOB conv columns,
// 66 scalar bf16 writes at physical unit (c>>3)^(slot&7) — the exact layout
// the verified MFMA loop reads (64 lanes/slot span 128 contiguous bytes:
// 2-way bank aliasing = free).
//   LEDGE  (w0==0):  loads w=0..67,  j = w+2;  patch v[0]=v[4], v[1]=v[3]
//   !LEDGE (w0==64): loads w=60..127, j = w-62; patch v[66]=v[64], v[67]=v[63]
// ---------------------------------------------------------------------------
template<bool LEDGE>
__device__ __forceinline__ void stage_row(const float* __restrict__ xb,
                                          unsigned short* sSp,
                                          int h0, int row, int c) {
    int hg = h0 - 1 + row;
    if (hg < 0 || hg > 127) return;   // OOB rows pre-zeroed (wave-uniform branch)
    const float* r0 = xb + (size_t)((hg == 0) ? 1 : hg - 1) * 128;
    const float* r1 = xb + (size_t)hg * 128;
    const float* r2 = xb + (size_t)((hg == 127) ? 126 : hg + 1) * 128;
    constexpr int xw0 = LEDGE ? 0 : 60;    // first loaded w (16B-aligned)
    constexpr int joff = LEDGE ? 2 : -2;   // j = (w - xw0) + joff

    // ---- load phase: all 51 loads issued before any use ----
    float4 la[17], lb[17], lc[17];
#pragma unroll
    for (int k = 0; k < 17; k++) la[k] = *(const float4*)(r0 + xw0 + 4 * k);
#pragma unroll
    for (int k = 0; k < 17; k++) lb[k] = *(const float4*)(r1 + xw0 + 4 * k);
#pragma unroll
    for (int k = 0; k < 17; k++) lc[k] = *(const float4*)(r2 + xw0 + 4 * k);

    // ---- sum phase (all indices compile-time) ----
    float v[68];
#pragma unroll
    for (int k = 0; k < 17; k++) {
        float s4[4] = {la[k].x + lb[k].x + lc[k].x, la[k].y + lb[k].y + lc[k].y,
                       la[k].z + lb[k].z + lc[k].z, la[k].w + lb[k].w + lc[k].w};
#pragma unroll
        for (int e = 0; e < 4; e++) {
            int j = 4 * k + e + joff;
            if (j >= 0 && j < 68) v[j] = s4[e];
        }
    }
    if (LEDGE) { v[0] = v[4]; v[1] = v[3]; }       // w=-2 -> w=2, w=-1 -> w=1
    else       { v[66] = v[64]; v[67] = v[63]; }   // w=128 -> 126, w=129 -> 125

    unsigned short* base = sSp + row * 4224 + (c & 7);
    int u8 = c >> 3;
#pragma unroll
    for (int slot = 0; slot < 66; slot++) {
        float sv = v[slot] + v[slot + 1] + v[slot + 2];   // wg = w0-1+slot
        if (LEDGE && slot == 0) sv = 0.f;     // wg=-1: conv zero-pad
        if (!LEDGE && slot == 65) sv = 0.f;   // wg=128: conv zero-pad
        base[slot * 64 + ((u8 ^ (slot & 7)) << 3)] = f2bf(sv);
    }
}

// ---------------------------------------------------------------------------
// Kernel 2: fused boxsum + implicit-GEMM conv, mfma_f32_32x32x16_bf16.
// Block = (b, 4 h-rows, 64-px w-tile), 4 waves; wave = 1 row x 64 px x 64 o
// (mf=2 x nf=2, acc[2][2] of f32x16). LDS tile: 6 rows x 66 slots x 64c bf16,
// 16B units XOR-swizzled g = u ^ (slot&7) — filled by stage_row from x.
// A from global Wt2 (lane-contiguous), tap-major prefetch. Grid 1024.
// ---------------------------------------------------------------------------
__global__ __launch_bounds__(256, 2) void fused_kernel(const float* __restrict__ x,
                                                       const unsigned short* __restrict__ Wt2,
                                                       float* __restrict__ out) {
    __shared__ __align__(16) unsigned short sS[6 * 66 * 64];   // 50688 B

    int bid = blockIdx.x;
    int b = bid >> 6;
    int h0 = ((bid >> 1) & 31) * 4;
    int w0 = (bid & 1) * 64;
    int tid = threadIdx.x;
    int lane = tid & 63;
    int wv = tid >> 6;
    int n32 = lane & 31;
    int q2 = lane >> 5;

    // pre-zero OOB rows (only image-edge strips)
    int4 z = make_int4(0, 0, 0, 0);
    if (h0 == 0)
        for (int i = tid; i < 528; i += 256) *(int4*)((char*)sS + (size_t)i * 16) = z;
    if (h0 == 124)
        for (int i = tid; i < 528; i += 256) *(int4*)((char*)sS + (size_t)(5 * 528 + i) * 16) = z;

    // ---- staging: 6 s-rows x 64 channels; thread = (c = tid&63, wave rw) ----
    {
        int c = lane;
        int rw = wv;
        const float* xb = x + ((size_t)(b * 64 + c)) * 16384;
        if (w0 == 0) {
            stage_row<true>(xb, sS, h0, rw, c);
            if (rw < 2) stage_row<true>(xb, sS, h0, 4 + rw, c);
        } else {
            stage_row<false>(xb, sS, h0, rw, c);
            if (rw < 2) stage_row<false>(xb, sS, h0, 4 + rw, c);
        }
    }

    // A-frags for tap 0: issued after staging stores (v[] dead -> no pressure
    // collision); latency overlaps the barrier wait.
    bf16x8 Af[8], An[8];
#pragma unroll
    for (int ic = 0; ic < 4; ic++)
#pragma unroll
        for (int mf = 0; mf < 2; mf++)
            Af[ic * 2 + mf] = *(const bf16x8*)(Wt2 + (((size_t)(0 * 4 + ic) * 2 + mf) * 64 + lane) * 8);
    __syncthreads();

    // B LDS offsets (shorts) per (kx, ic); add (wv+ky)*4224 + nf*2048
    int p0[3][4];
#pragma unroll
    for (int kx = 0; kx < 3; kx++)
#pragma unroll
        for (int ic = 0; ic < 4; ic++) {
            int slot = n32 + kx;
            int g = (ic * 2 + q2) ^ (slot & 7);
            p0[kx][ic] = slot * 64 + g * 8;
        }

    f32x16 acc[2][2];
#pragma unroll
    for (int mf = 0; mf < 2; mf++)
#pragma unroll
        for (int nf = 0; nf < 2; nf++)
#pragma unroll
            for (int r = 0; r < 16; r++) acc[mf][nf][r] = 0.f;

#pragma unroll
    for (int tap = 0; tap < 9; tap++) {
        int ky = tap / 3, kx = tap % 3;
        if (tap < 8) {
#pragma unroll
            for (int ic = 0; ic < 4; ic++)
#pragma unroll
                for (int mf = 0; mf < 2; mf++)
                    An[ic * 2 + mf] = *(const bf16x8*)(Wt2 + (((size_t)((tap + 1) * 4 + ic) * 2 + mf) * 64 + lane) * 8);
        }
#pragma unroll
        for (int ic = 0; ic < 4; ic++) {
            const unsigned short* bp = sS + (size_t)(wv + ky) * 4224 + p0[kx][ic];
            bf16x8 b0 = *(const bf16x8*)(bp);
            bf16x8 b1 = *(const bf16x8*)(bp + 2048);
            acc[0][0] = __builtin_amdgcn_mfma_f32_32x32x16_bf16(Af[ic * 2 + 0], b0, acc[0][0], 0, 0, 0);
            acc[0][1] = __builtin_amdgcn_mfma_f32_32x32x16_bf16(Af[ic * 2 + 0], b1, acc[0][1], 0, 0, 0);
            acc[1][0] = __builtin_amdgcn_mfma_f32_32x32x16_bf16(Af[ic * 2 + 1], b0, acc[1][0], 0, 0, 0);
            acc[1][1] = __builtin_amdgcn_mfma_f32_32x32x16_bf16(Af[ic * 2 + 1], b1, acc[1][1], 0, 0, 0);
        }
        if (tap < 8) {
#pragma unroll
            for (int k = 0; k < 8; k++) Af[k] = An[k];
        }
    }

    // epilogue: 32x32 C/D layout col=lane&31 (pixel), row=(r&3)+8*(r>>2)+4*q2 (o)
    float* ob = out + ((size_t)b * 64) * 16384 + (size_t)(h0 + wv) * 128 + w0;
#pragma unroll
    for (int mf = 0; mf < 2; mf++)
#pragma unroll
        for (int nf = 0; nf < 2; nf++)
#pragma unroll
            for (int r = 0; r < 16; r++) {
                int o = mf * 32 + (r & 3) + 8 * (r >> 2) + 4 * q2;
                ob[(size_t)o * 16384 + nf * 32 + n32] = acc[mf][nf][r];
            }
}

// ---------------------------------------------------------------------------
extern "C" void kernel_launch(void* const* d_in, const int* in_sizes, int n_in,
                              void* d_out, int out_size, void* d_ws, size_t ws_size,
                              hipStream_t stream) {
    const float* x = (const float*)d_in[0];   // [16][64][128][128] fp32
    const float* W = (const float*)d_in[1];   // [64][64][3][3] fp32
    float* outp = (float*)d_out;

    // ws: Wt2 bf16 (73728 B); no global s intermediate
    unsigned short* Wt2 = (unsigned short*)d_ws;

    weff_kernel<<<2, 256, 0, stream>>>(W, Wt2);
    fused_kernel<<<1024, 256, 0, stream>>>(x, Wt2, outp);
}

// Round 5
// 166.289 us; speedup vs baseline: 1.0222x; 1.0222x over previous
//
#include <hip/hip_runtime.h>
#include <stdint.h>

// out = conv3x3_zeropad(s, W_eff), s = 3x3 reflect-pad box sum of x (B=16,C=64,H=W=128)
// R10: fused kernel (R8 structure, verified passing) with LINE-LEVEL MLP fix:
// per staging pass each lane touches 9 distinct 128B cache lines; issue the 9
// line-opening loads (k=0,8,16 of each of 3 rows) FIRST, pinned by
// sched_barrier(0), so ~9 lines/wave are in flight (was 1-2 -> measured 29%
// HBM). Body loads then hit L1. Af prefetch before staging (R8 position).
// MFMA loop / swizzle / epilogue / weff byte-identical to verified kernels.

#define THETA 0.7f

typedef __attribute__((ext_vector_type(8))) short bf16x8;
typedef __attribute__((ext_vector_type(16))) float f32x16;

__device__ inline unsigned short f2bf(float f) {
    unsigned u = __float_as_uint(f);
    u = (u + 0x7FFFu + ((u >> 16) & 1u)) >> 16;   // RNE
    return (unsigned short)u;
}

// ---------------------------------------------------------------------------
// Kernel 1: W_eff -> Wt2 bf16, lane-contiguous MFMA-A layout (verified):
// Wt2[(((tap*4+ic)*2+mf)*64 + lane)*8 + j] = W_eff[o][ch][tap]
//   o = mf*32 + (lane&31), ch = ic*16 + (lane>>5)*8 + j
// ---------------------------------------------------------------------------
__global__ void weff_kernel(const float* __restrict__ W, unsigned short* __restrict__ Wt2) {
    int t = blockIdx.x * blockDim.x + threadIdx.x;   // 512 threads
    if (t >= 512) return;
    int o = t >> 3;
    int ch8 = t & 7;
    int c0 = ch8 * 8;
    int ic = ch8 >> 1;
    int mf = o >> 5;
    int lane = (o & 31) | ((ch8 & 1) << 5);

    float v[8][9];
    float tsum[8];
#pragma unroll
    for (int j = 0; j < 8; j++) {
        const float* w = W + ((size_t)o * 64 + c0 + j) * 9;
        float sum = 0.f;
#pragma unroll
        for (int k = 0; k < 9; k++) { v[j][k] = w[k]; sum += v[j][k]; }
        tsum[j] = sum;
    }
#pragma unroll
    for (int tap = 0; tap < 9; tap++) {
        unsigned short* dst = Wt2 + (((size_t)(tap * 4 + ic) * 2 + mf) * 64 + lane) * 8;
#pragma unroll
        for (int j = 0; j < 8; j++) {
            float val = v[j][tap] - ((tap == 4) ? THETA * tsum[j] : 0.f);
            dst[j] = f2bf(val);
        }
    }
}

// ---------------------------------------------------------------------------
// Staging: one s-row (66 slots x 64 ch) of the conv LDS tile, computed from x.
// Thread owns channel c (NCHW: lanes hit 64 distinct 64KB-strided planes, so
// MLP is LINE-level: 9 distinct 128B lines per pass). HEAD PHASE opens all 9
// lines (k=0,8,16 x 3 rows) and is pinned by sched_barrier(0); BODY loads are
// L1 hits. SUM PHASE: vertical 3-sum into statically-indexed v[68], register
// reflect-patches, horizontal 3-sum, zero-pad OOB conv columns, 66 scalar
// bf16 writes at physical unit (c>>3)^(slot&7) — the exact layout the MFMA
// loop reads (64 lanes/slot span 128 contiguous bytes: 2-way aliasing, free).
//   LEDGE  (w0==0):  loads w=0..67,  j = w+2;  patch v[0]=v[4], v[1]=v[3]
//   !LEDGE (w0==64): loads w=60..127, j = w-62; patch v[66]=v[64], v[67]=v[63]
// ---------------------------------------------------------------------------
template<bool LEDGE>
__device__ __forceinline__ void stage_row(const float* __restrict__ xb,
                                          unsigned short* sSp,
                                          int h0, int row, int c) {
    int hg = h0 - 1 + row;
    if (hg < 0 || hg > 127) return;   // OOB rows pre-zeroed (wave-uniform branch)
    const float* r0 = xb + (size_t)((hg == 0) ? 1 : hg - 1) * 128;
    const float* r1 = xb + (size_t)hg * 128;
    const float* r2 = xb + (size_t)((hg == 127) ? 126 : hg + 1) * 128;
    constexpr int xw0 = LEDGE ? 0 : 60;    // first loaded w (16B-aligned)
    constexpr int joff = LEDGE ? 2 : -2;   // j = (w - xw0) + joff

    float4 la[17], lb[17], lc[17];
    // ---- head phase: open all 9 cache lines, pinned first ----
    la[0] = *(const float4*)(r0 + xw0);
    la[8] = *(const float4*)(r0 + xw0 + 32);
    la[16] = *(const float4*)(r0 + xw0 + 64);
    lb[0] = *(const float4*)(r1 + xw0);
    lb[8] = *(const float4*)(r1 + xw0 + 32);
    lb[16] = *(const float4*)(r1 + xw0 + 64);
    lc[0] = *(const float4*)(r2 + xw0);
    lc[8] = *(const float4*)(r2 + xw0 + 32);
    lc[16] = *(const float4*)(r2 + xw0 + 64);
    __builtin_amdgcn_sched_barrier(0);   // heads may not sink below this point

    // ---- body phase: L1 hits on the opened lines ----
#pragma unroll
    for (int k = 0; k < 17; k++) {
        if (k == 0 || k == 8 || k == 16) continue;
        la[k] = *(const float4*)(r0 + xw0 + 4 * k);
        lb[k] = *(const float4*)(r1 + xw0 + 4 * k);
        lc[k] = *(const float4*)(r2 + xw0 + 4 * k);
    }

    // ---- sum phase (all indices compile-time) ----
    float v[68];
#pragma unroll
    for (int k = 0; k < 17; k++) {
        float s4[4] = {la[k].x + lb[k].x + lc[k].x, la[k].y + lb[k].y + lc[k].y,
                       la[k].z + lb[k].z + lc[k].z, la[k].w + lb[k].w + lc[k].w};
#pragma unroll
        for (int e = 0; e < 4; e++) {
            int j = 4 * k + e + joff;
            if (j >= 0 && j < 68) v[j] = s4[e];
        }
    }
    if (LEDGE) { v[0] = v[4]; v[1] = v[3]; }       // w=-2 -> w=2, w=-1 -> w=1
    else       { v[66] = v[64]; v[67] = v[63]; }   // w=128 -> 126, w=129 -> 125

    unsigned short* base = sSp + row * 4224 + (c & 7);
    int u8 = c >> 3;
#pragma unroll
    for (int slot = 0; slot < 66; slot++) {
        float sv = v[slot] + v[slot + 1] + v[slot + 2];   // wg = w0-1+slot
        if (LEDGE && slot == 0) sv = 0.f;     // wg=-1: conv zero-pad
        if (!LEDGE && slot == 65) sv = 0.f;   // wg=128: conv zero-pad
        base[slot * 64 + ((u8 ^ (slot & 7)) << 3)] = f2bf(sv);
    }
}

// ---------------------------------------------------------------------------
// Kernel 2: fused boxsum + implicit-GEMM conv, mfma_f32_32x32x16_bf16.
// Block = (b, 4 h-rows, 64-px w-tile), 4 waves; wave = 1 row x 64 px x 64 o
// (mf=2 x nf=2, acc[2][2] of f32x16). LDS tile: 6 rows x 66 slots x 64c bf16,
// 16B units XOR-swizzled g = u ^ (slot&7) — filled by stage_row from x.
// A from global Wt2 (lane-contiguous), tap-major prefetch. Grid 1024.
// ---------------------------------------------------------------------------
__global__ __launch_bounds__(256, 2) void fused_kernel(const float* __restrict__ x,
                                                       const unsigned short* __restrict__ Wt2,
                                                       float* __restrict__ out) {
    __shared__ __align__(16) unsigned short sS[6 * 66 * 64];   // 50688 B

    int bid = blockIdx.x;
    int b = bid >> 6;
    int h0 = ((bid >> 1) & 31) * 4;
    int w0 = (bid & 1) * 64;
    int tid = threadIdx.x;
    int lane = tid & 63;
    int wv = tid >> 6;
    int n32 = lane & 31;
    int q2 = lane >> 5;

    // pre-zero OOB rows (only image-edge strips)
    int4 z = make_int4(0, 0, 0, 0);
    if (h0 == 0)
        for (int i = tid; i < 528; i += 256) *(int4*)((char*)sS + (size_t)i * 16) = z;
    if (h0 == 124)
        for (int i = tid; i < 528; i += 256) *(int4*)((char*)sS + (size_t)(5 * 528 + i) * 16) = z;

    // A-frags for tap 0: issued first — 8 more independent loads in flight,
    // consumed only in the MFMA phase (R8-verified position).
    bf16x8 Af[8], An[8];
#pragma unroll
    for (int ic = 0; ic < 4; ic++)
#pragma unroll
        for (int mf = 0; mf < 2; mf++)
            Af[ic * 2 + mf] = *(const bf16x8*)(Wt2 + (((size_t)(0 * 4 + ic) * 2 + mf) * 64 + lane) * 8);

    // ---- staging: 6 s-rows x 64 channels; thread = (c = tid&63, wave rw) ----
    {
        int c = lane;
        int rw = wv;
        const float* xb = x + ((size_t)(b * 64 + c)) * 16384;
        if (w0 == 0) {
            stage_row<true>(xb, sS, h0, rw, c);
            if (rw < 2) stage_row<true>(xb, sS, h0, 4 + rw, c);
        } else {
            stage_row<false>(xb, sS, h0, rw, c);
            if (rw < 2) stage_row<false>(xb, sS, h0, 4 + rw, c);
        }
    }
    __syncthreads();

    // B LDS offsets (shorts) per (kx, ic); add (wv+ky)*4224 + nf*2048
    int p0[3][4];
#pragma unroll
    for (int kx = 0; kx < 3; kx++)
#pragma unroll
        for (int ic = 0; ic < 4; ic++) {
            int slot = n32 + kx;
            int g = (ic * 2 + q2) ^ (slot & 7);
            p0[kx][ic] = slot * 64 + g * 8;
        }

    f32x16 acc[2][2];
#pragma unroll
    for (int mf = 0; mf < 2; mf++)
#pragma unroll
        for (int nf = 0; nf < 2; nf++)
#pragma unroll
            for (int r = 0; r < 16; r++) acc[mf][nf][r] = 0.f;

#pragma unroll
    for (int tap = 0; tap < 9; tap++) {
        int ky = tap / 3, kx = tap % 3;
        if (tap < 8) {
#pragma unroll
            for (int ic = 0; ic < 4; ic++)
#pragma unroll
                for (int mf = 0; mf < 2; mf++)
                    An[ic * 2 + mf] = *(const bf16x8*)(Wt2 + (((size_t)((tap + 1) * 4 + ic) * 2 + mf) * 64 + lane) * 8);
        }
#pragma unroll
        for (int ic = 0; ic < 4; ic++) {
            const unsigned short* bp = sS + (size_t)(wv + ky) * 4224 + p0[kx][ic];
            bf16x8 b0 = *(const bf16x8*)(bp);
            bf16x8 b1 = *(const bf16x8*)(bp + 2048);
            acc[0][0] = __builtin_amdgcn_mfma_f32_32x32x16_bf16(Af[ic * 2 + 0], b0, acc[0][0], 0, 0, 0);
            acc[0][1] = __builtin_amdgcn_mfma_f32_32x32x16_bf16(Af[ic * 2 + 0], b1, acc[0][1], 0, 0, 0);
            acc[1][0] = __builtin_amdgcn_mfma_f32_32x32x16_bf16(Af[ic * 2 + 1], b0, acc[1][0], 0, 0, 0);
            acc[1][1] = __builtin_amdgcn_mfma_f32_32x32x16_bf16(Af[ic * 2 + 1], b1, acc[1][1], 0, 0, 0);
        }
        if (tap < 8) {
#pragma unroll
            for (int k = 0; k < 8; k++) Af[k] = An[k];
        }
    }

    // epilogue: 32x32 C/D layout col=lane&31 (pixel), row=(r&3)+8*(r>>2)+4*q2 (o)
    float* ob = out + ((size_t)b * 64) * 16384 + (size_t)(h0 + wv) * 128 + w0;
#pragma unroll
    for (int mf = 0; mf < 2; mf++)
#pragma unroll
        for (int nf = 0; nf < 2; nf++)
#pragma unroll
            for (int r = 0; r < 16; r++) {
                int o = mf * 32 + (r & 3) + 8 * (r >> 2) + 4 * q2;
                ob[(size_t)o * 16384 + nf * 32 + n32] = acc[mf][nf][r];
            }
}

// ---------------------------------------------------------------------------
extern "C" void kernel_launch(void* const* d_in, const int* in_sizes, int n_in,
                              void* d_out, int out_size, void* d_ws, size_t ws_size,
                              hipStream_t stream) {
    const float* x = (const float*)d_in[0];   // [16][64][128][128] fp32
    const float* W = (const float*)d_in[1];   // [64][64][3][3] fp32
    float* outp = (float*)d_out;

    // ws: Wt2 bf16 (73728 B); no global s intermediate
    unsigned short* Wt2 = (unsigned short*)d_ws;

    weff_kernel<<<2, 256, 0, stream>>>(W, Wt2);
    fused_kernel<<<1024, 256, 0, stream>>>(x, Wt2, outp);
}

// Round 6
// 142.929 us; speedup vs baseline: 1.1893x; 1.1634x over previous
//
#include <hip/hip_runtime.h>
#include <stdint.h>

// out = conv3x3_zeropad(s, W_eff), s = 3x3 reflect-pad box sum of x (B=16,C=64,H=W=128)
// R11: fused kernel with COALESCED staging. R3-R5 showed channel-per-thread
// staging is VMEM-request-bound (64 scattered lines per load instr; 30% HBM,
// all pipes idle, MLP fixes null). New block = (b, 4h, FULL 128w), 512 thr:
// staging thread = (w4, 4 ch), 32-lane contiguous float4 row loads (8 lines
// per instr), rolling vertical sums, boxsumT-verified shfl horizontal,
// ushort4 channel-packed writes into the swizzled unit layout (c>>3)^(slot&7)
// the MFMA loop reads. MFMA per-wave math identical (w0 = (wv&1)*64).

#define THETA 0.7f

typedef __attribute__((ext_vector_type(8))) short bf16x8;
typedef __attribute__((ext_vector_type(16))) float f32x16;

__device__ inline unsigned short f2bf(float f) {
    unsigned u = __float_as_uint(f);
    u = (u + 0x7FFFu + ((u >> 16) & 1u)) >> 16;   // RNE
    return (unsigned short)u;
}

// ---------------------------------------------------------------------------
// Kernel 1: W_eff -> Wt2 bf16, lane-contiguous MFMA-A layout (verified):
// Wt2[(((tap*4+ic)*2+mf)*64 + lane)*8 + j] = W_eff[o][ch][tap]
//   o = mf*32 + (lane&31), ch = ic*16 + (lane>>5)*8 + j
// ---------------------------------------------------------------------------
__global__ void weff_kernel(const float* __restrict__ W, unsigned short* __restrict__ Wt2) {
    int t = blockIdx.x * blockDim.x + threadIdx.x;   // 512 threads
    if (t >= 512) return;
    int o = t >> 3;
    int ch8 = t & 7;
    int c0 = ch8 * 8;
    int ic = ch8 >> 1;
    int mf = o >> 5;
    int lane = (o & 31) | ((ch8 & 1) << 5);

    float v[8][9];
    float tsum[8];
#pragma unroll
    for (int j = 0; j < 8; j++) {
        const float* w = W + ((size_t)o * 64 + c0 + j) * 9;
        float sum = 0.f;
#pragma unroll
        for (int k = 0; k < 9; k++) { v[j][k] = w[k]; sum += v[j][k]; }
        tsum[j] = sum;
    }
#pragma unroll
    for (int tap = 0; tap < 9; tap++) {
        unsigned short* dst = Wt2 + (((size_t)(tap * 4 + ic) * 2 + mf) * 64 + lane) * 8;
#pragma unroll
        for (int j = 0; j < 8; j++) {
            float val = v[j][tap] - ((tap == 4) ? THETA * tsum[j] : 0.f);
            dst[j] = f2bf(val);
        }
    }
}

// ---------------------------------------------------------------------------
// Kernel 2: fused boxsum + implicit-GEMM conv, mfma_f32_32x32x16_bf16.
// Block = (b, 4 h-rows, full 128-px width), 8 waves; wave = 1 row x 64 px
// (half = wv&1) x 64 o (mf=2 x nf=2, acc[2][2] of f32x16).
// LDS s-tile: [6 rows][132 slots][64 c] bf16 = 101376 B; slot = w+1
// (slots 0 / 129 = conv zero-pad, zeroed); 16B units XOR-swizzled
// p = (c>>3) ^ (slot&7). Grid 512 = 16 b x 32 strips.
// ---------------------------------------------------------------------------
__global__ __launch_bounds__(512, 2) void fused_kernel(const float* __restrict__ x,
                                                       const unsigned short* __restrict__ Wt2,
                                                       float* __restrict__ out) {
    __shared__ __align__(16) unsigned short sS[6 * 132 * 64];   // 101376 B

    int bid = blockIdx.x;
    int b = bid >> 5;
    int h0 = (bid & 31) * 4;
    int tid = threadIdx.x;
    int lane = tid & 63;
    int wv = tid >> 6;          // 0..7
    int n32 = lane & 31;
    int q2 = lane >> 5;
    int orow = wv >> 1;         // out row within tile (0..3)
    int whalf = wv & 1;         // which 64-px half

    // zero-pad slots 0 (w=-1) and 129 (w=128), all 6 rows: 96 x 16B
    int4 z = make_int4(0, 0, 0, 0);
    if (tid < 96) {
        int rr = tid >> 4;
        int sl = ((tid & 15) >> 3) ? 129 : 0;
        int g = tid & 7;
        *(int4*)((char*)sS + ((size_t)(rr * 132 + sl) * 8 + g) * 16) = z;
    }
    // zero OOB rows at image edges (staging skips them)
    if (h0 == 0)
        for (int i = tid; i < 1056; i += 512) *(int4*)((char*)sS + (size_t)i * 16) = z;
    if (h0 == 124)
        for (int i = tid; i < 1056; i += 512) *(int4*)((char*)sS + (size_t)(5280 + i) * 16) = z;

    // A-frags for tap 0: issued early, consumed post-barrier
    bf16x8 Af[8], An[8];
#pragma unroll
    for (int ic = 0; ic < 4; ic++)
#pragma unroll
        for (int mf = 0; mf < 2; mf++)
            Af[ic * 2 + mf] = *(const bf16x8*)(Wt2 + (((size_t)(0 * 4 + ic) * 2 + mf) * 64 + lane) * 8);

    // ---- coalesced staging: thread = (w4 = tid&31, cg = tid>>5 -> 4 ch) ----
    {
        int w4 = tid & 31;
        int cg = tid >> 5;          // 0..15
        int c0 = cg * 4;
        int u8 = cg >> 1;           // 16B unit (8 channels)
        int hh = (cg & 1) * 4;      // shorts offset within unit
        const float* xp = x + ((size_t)(b * 64 + c0)) * 16384 + w4 * 4;

        int hgf = (h0 == 0) ? 0 : h0 - 1;         // first valid s-row
        int hm = (hgf == 0) ? 1 : hgf - 1;        // vertical reflect up
        float4 A[4], Bv[4], C[4];
#pragma unroll
        for (int cc = 0; cc < 4; cc++) {
            A[cc]  = *(const float4*)(xp + (size_t)cc * 16384 + (size_t)hm * 128);
            Bv[cc] = *(const float4*)(xp + (size_t)cc * 16384 + (size_t)hgf * 128);
            C[cc]  = *(const float4*)(xp + (size_t)cc * 16384 + (size_t)(hgf + 1) * 128);
        }

#pragma unroll
        for (int rr = 0; rr < 6; rr++) {
            int hg = h0 - 1 + rr;
            if (hg < 0 || hg > 127) continue;     // block-uniform skip (pre-zeroed)

            float4 Cn[4];
            if (rr < 5) {
                int hn = hg + 2;
                if (hn > 127) hn = 126;           // vertical reflect down
#pragma unroll
                for (int cc = 0; cc < 4; cc++)
                    Cn[cc] = *(const float4*)(xp + (size_t)cc * 16384 + (size_t)hn * 128);
            }

            unsigned short res[4][4];   // [cc][k]
#pragma unroll
            for (int cc = 0; cc < 4; cc++) {
                float4 vs;
                vs.x = A[cc].x + Bv[cc].x + C[cc].x;
                vs.y = A[cc].y + Bv[cc].y + C[cc].y;
                vs.z = A[cc].z + Bv[cc].z + C[cc].z;
                vs.w = A[cc].w + Bv[cc].w + C[cc].w;
                float L = __shfl_up(vs.w, 1, 32);
                float R = __shfl_down(vs.x, 1, 32);
                float sx = (w4 == 0) ? vs.x + 2.f * vs.y : L + vs.x + vs.y;
                float sy = vs.x + vs.y + vs.z;
                float sz = vs.y + vs.z + vs.w;
                float sw_ = (w4 == 31) ? 2.f * vs.z + vs.w : vs.z + vs.w + R;
                res[cc][0] = f2bf(sx);
                res[cc][1] = f2bf(sy);
                res[cc][2] = f2bf(sz);
                res[cc][3] = f2bf(sw_);
            }
            // write 4 ushort4 (channel-packed) into swizzled units
#pragma unroll
            for (int k = 0; k < 4; k++) {
                int slot = w4 * 4 + k + 1;        // w = w4*4+k -> slot w+1
                ushort4 o4 = make_ushort4(res[0][k], res[1][k], res[2][k], res[3][k]);
                *(ushort4*)(sS + (size_t)(rr * 132 + slot) * 64 + ((u8 ^ (slot & 7)) << 3) + hh) = o4;
            }
            if (rr < 5) {
#pragma unroll
                for (int cc = 0; cc < 4; cc++) { A[cc] = Bv[cc]; Bv[cc] = C[cc]; C[cc] = Cn[cc]; }
            }
        }
    }
    __syncthreads();

    // B LDS offsets (shorts) per (kx, ic); add (orow+ky)*8448 + nf*2048
    int p0[3][4];
#pragma unroll
    for (int kx = 0; kx < 3; kx++)
#pragma unroll
        for (int ic = 0; ic < 4; ic++) {
            int slot = n32 + kx + whalf * 64;
            int g = (ic * 2 + q2) ^ (slot & 7);   // (slot+64)&7 == slot&7
            p0[kx][ic] = slot * 64 + g * 8;
        }

    f32x16 acc[2][2];
#pragma unroll
    for (int mf = 0; mf < 2; mf++)
#pragma unroll
        for (int nf = 0; nf < 2; nf++)
#pragma unroll
            for (int r = 0; r < 16; r++) acc[mf][nf][r] = 0.f;

#pragma unroll
    for (int tap = 0; tap < 9; tap++) {
        int ky = tap / 3, kx = tap % 3;
        if (tap < 8) {
#pragma unroll
            for (int ic = 0; ic < 4; ic++)
#pragma unroll
                for (int mf = 0; mf < 2; mf++)
                    An[ic * 2 + mf] = *(const bf16x8*)(Wt2 + (((size_t)((tap + 1) * 4 + ic) * 2 + mf) * 64 + lane) * 8);
        }
#pragma unroll
        for (int ic = 0; ic < 4; ic++) {
            const unsigned short* bp = sS + (size_t)(orow + ky) * 8448 + p0[kx][ic];
            bf16x8 b0 = *(const bf16x8*)(bp);
            bf16x8 b1 = *(const bf16x8*)(bp + 2048);
            acc[0][0] = __builtin_amdgcn_mfma_f32_32x32x16_bf16(Af[ic * 2 + 0], b0, acc[0][0], 0, 0, 0);
            acc[0][1] = __builtin_amdgcn_mfma_f32_32x32x16_bf16(Af[ic * 2 + 0], b1, acc[0][1], 0, 0, 0);
            acc[1][0] = __builtin_amdgcn_mfma_f32_32x32x16_bf16(Af[ic * 2 + 1], b0, acc[1][0], 0, 0, 0);
            acc[1][1] = __builtin_amdgcn_mfma_f32_32x32x16_bf16(Af[ic * 2 + 1], b1, acc[1][1], 0, 0, 0);
        }
        if (tap < 8) {
#pragma unroll
            for (int k = 0; k < 8; k++) Af[k] = An[k];
        }
    }

    // epilogue: 32x32 C/D layout col=lane&31 (pixel), row=(r&3)+8*(r>>2)+4*q2 (o)
    float* ob = out + ((size_t)b * 64) * 16384 + (size_t)(h0 + orow) * 128 + whalf * 64;
#pragma unroll
    for (int mf = 0; mf < 2; mf++)
#pragma unroll
        for (int nf = 0; nf < 2; nf++)
#pragma unroll
            for (int r = 0; r < 16; r++) {
                int o = mf * 32 + (r & 3) + 8 * (r >> 2) + 4 * q2;
                ob[(size_t)o * 16384 + nf * 32 + n32] = acc[mf][nf][r];
            }
}

// ---------------------------------------------------------------------------
extern "C" void kernel_launch(void* const* d_in, const int* in_sizes, int n_in,
                              void* d_out, int out_size, void* d_ws, size_t ws_size,
                              hipStream_t stream) {
    const float* x = (const float*)d_in[0];   // [16][64][128][128] fp32
    const float* W = (const float*)d_in[1];   // [64][64][3][3] fp32
    float* outp = (float*)d_out;

    // ws: Wt2 bf16 (73728 B); no global s intermediate
    unsigned short* Wt2 = (unsigned short*)d_ws;

    weff_kernel<<<2, 256, 0, stream>>>(W, Wt2);
    fused_kernel<<<512, 512, 0, stream>>>(x, Wt2, outp);
}